// Round 14
// baseline (1591.286 us; speedup 1.0000x reference)
//
#include <hip/hip_runtime.h>
#include <cstdint>

// ---------- types ----------
typedef __bf16 bf16x8 __attribute__((ext_vector_type(8)));
typedef float  f32x4  __attribute__((ext_vector_type(4)));

// Problem constants: BATCH=8, N_SEQS=4, SEQ_LEN=2048, D=512 -> 32 seqs, 65536 rows
#define SEQS   32
#define SLEN   2048
#define DIM    512
#define MROWS  65536

static __device__ __forceinline__ void load_lds16(const void* g, void* l) {
  __builtin_amdgcn_global_load_lds(
      (const __attribute__((address_space(1))) void*)(uintptr_t)g,
      (__attribute__((address_space(3))) void*)(uintptr_t)l,
      16, 0, 0);
}

static __device__ __forceinline__ unsigned short bfbits(float f) {
  __bf16 h = (__bf16)f;
  unsigned short u;
  __builtin_memcpy(&u, &h, 2);
  return u;
}

// ---------- kernels ----------

// One dispatch: cast x (fp32->bf16) plus the 4 weight matrices.
__global__ __launch_bounds__(256) void castall_kernel(
    const float* __restrict__ x, __bf16* __restrict__ xb,
    const float* __restrict__ wq, const float* __restrict__ wk,
    const float* __restrict__ wv, const float* __restrict__ wo,
    __bf16* __restrict__ wqb, __bf16* __restrict__ wkb,
    __bf16* __restrict__ wvb, __bf16* __restrict__ wob)
{
  const int X8 = MROWS * DIM / 8;            // 4,194,304
  const int W8 = DIM * DIM / 8;              // 32,768
  const int total = X8 + 4 * W8;
  int i = blockIdx.x * blockDim.x + threadIdx.x;
  const int stride = gridDim.x * blockDim.x;
  for (; i < total; i += stride) {
    const float* src; __bf16* dst; int off;
    if (i < X8) { src = x; dst = xb; off = i; }
    else {
      const int wsel = (i - X8) / W8;
      off = (i - X8) - wsel * W8;
      src = (wsel == 0) ? wq : (wsel == 1) ? wk : (wsel == 2) ? wv : wo;
      dst = (wsel == 0) ? wqb : (wsel == 1) ? wkb : (wsel == 2) ? wvb : wob;
    }
    const float4* p = reinterpret_cast<const float4*>(src + (size_t)off * 8);
    float4 a = p[0], b2 = p[1];
    float vals[8] = {a.x, a.y, a.z, a.w, b2.x, b2.y, b2.z, b2.w};
    uint32_t w[4];
#pragma unroll
    for (int t = 0; t < 4; ++t)
      w[t] = (uint32_t)bfbits(vals[2 * t]) | ((uint32_t)bfbits(vals[2 * t + 1]) << 16);
    uint4 o; o.x = w[0]; o.y = w[1]; o.z = w[2]; o.w = w[3];
    *reinterpret_cast<uint4*>(dst + (size_t)off * 8) = o;
  }
}

// QKV projection: 256x256 tile, 512 threads (8 waves 2Mx4N), BK=64,
// SINGLE-buffer LDS (64KB) + two __syncthreads per K-step (r1-verified
// pattern). 64KB -> 2 blocks/CU co-resident (VGPR capped 128 via
// __launch_bounds__(512,4); r13 measured 116): block A's stage/drain
// overlaps block B's MFMA (m97/m114 regime) — replaces the dbuf-128KB
// 1-barrier form that was stuck at 1 block/CU / 741 TF.
// 128B rows -> slot^(r&7) swizzle on stage + read (0 conflicts, verified).
__global__ __launch_bounds__(512, 4) void qkv_kernel(
    const __bf16* __restrict__ xb,
    const __bf16* __restrict__ Wqb, const __bf16* __restrict__ Wkb,
    const __bf16* __restrict__ Wvb,
    __bf16* __restrict__ Q, __bf16* __restrict__ KT, __bf16* __restrict__ VT,
    float* __restrict__ ksum)
{
  __shared__ __align__(16) __bf16 As[256 * 64];   // 32KB
  __shared__ __align__(16) __bf16 Bs[256 * 64];   // 32KB
  const int b = blockIdx.x;
  const int xcd = b & 7, loc = b >> 3;
  const int brow = (loc / 6) * 8 + xcd;          // 0..255
  const int inner = loc % 6;
  const int z = inner >> 1, bcol = inner & 1;
  const __bf16* W = (z == 0) ? Wqb : (z == 1) ? Wkb : Wvb;

  const int tid = threadIdx.x, wave = tid >> 6, lane = tid & 63;
  const int wr = wave >> 2, wn = wave & 3;       // 2 M-halves x 4 N-quarters
  const int lr = lane & 15, kq = lane >> 4;

  const __bf16* Abase = xb + (size_t)(brow * 256) * DIM;
  const __bf16* Bbase = W + (size_t)(bcol * 256) * DIM;

  auto stage = [&](int kt) {
#pragma unroll
    for (int q = 0; q < 4; ++q) {
      const int L  = q * 8192 + tid * 16;
      const int r  = L >> 7;
      const int sl = (L >> 4) & 7;
      const int c  = ((sl ^ (r & 7)) << 3);
      load_lds16(Abase + (size_t)r * DIM + (kt + c),
                 (char*)As + q * 8192 + wave * 1024);
      load_lds16(Bbase + (size_t)r * DIM + (kt + c),
                 (char*)Bs + q * 8192 + wave * 1024);
    }
  };

  f32x4 acc[8][4] = {};

  for (int t = 0; t < 8; ++t) {
    stage(t * 64);
    __syncthreads();                 // drain: tile visible
#pragma unroll
    for (int kk = 0; kk < 2; ++kk) {
      bf16x8 bfr[4], af[8];
#pragma unroll
      for (int j = 0; j < 4; ++j) {
        const int rB = wn * 64 + j * 16 + lr;
        bfr[j] = *reinterpret_cast<const bf16x8*>(
            (const char*)Bs + rB * 128 + (((kk * 4 + kq) ^ (rB & 7)) << 4));
      }
#pragma unroll
      for (int i = 0; i < 8; ++i) {
        const int rA = wr * 128 + i * 16 + lr;
        af[i] = *reinterpret_cast<const bf16x8*>(
            (const char*)As + rA * 128 + (((kk * 4 + kq) ^ (rA & 7)) << 4));
      }
#pragma unroll
      for (int i = 0; i < 8; ++i)
#pragma unroll
        for (int j = 0; j < 4; ++j)
          acc[i][j] = __builtin_amdgcn_mfma_f32_16x16x32_bf16(af[i], bfr[j], acc[i][j], 0, 0, 0);
    }
    __syncthreads();                 // protect buffer before next stage
  }

  // epilogue
  const int m00 = brow * 256 + wr * 128 + kq * 4;
  const int n00 = bcol * 256 + wn * 64 + lr;
  if (z == 0) {
#pragma unroll
    for (int i = 0; i < 8; ++i)
#pragma unroll
      for (int j = 0; j < 4; ++j) {
        const int n = n00 + j * 16;
#pragma unroll
        for (int r = 0; r < 4; ++r) {
          const int m = m00 + i * 16 + r;
          float v = acc[i][j][r];
          v = (v > 0.f) ? (v + 1.f) : __expf(v);   // elu(v)+1
          Q[(size_t)m * DIM + n] = (__bf16)v;
        }
      }
  } else {
    __bf16* T = (z == 1) ? KT : VT;
    const int seq = (brow * 256) >> 11;
    float ks[4] = {0.f, 0.f, 0.f, 0.f};
#pragma unroll
    for (int i = 0; i < 8; ++i) {
      const int mb = m00 + i * 16;
      const int s0 = mb & 2047;
#pragma unroll
      for (int j = 0; j < 4; ++j) {
        const int d = n00 + j * 16;
        unsigned short h[4];
#pragma unroll
        for (int r = 0; r < 4; ++r) {
          float v = acc[i][j][r];
          if (z == 1) { v = (v > 0.f) ? (v + 1.f) : __expf(v); ks[j] += v; }
          h[r] = bfbits(v);
        }
        uint2 u;
        u.x = (uint32_t)h[0] | ((uint32_t)h[1] << 16);
        u.y = (uint32_t)h[2] | ((uint32_t)h[3] << 16);
        *reinterpret_cast<uint2*>(T + ((size_t)(seq * DIM + d) << 11) + s0) = u;
      }
    }
    if (z == 1) {
#pragma unroll
      for (int j = 0; j < 4; ++j) {
        float p = ks[j];
        p += __shfl_xor(p, 16, 64);
        p += __shfl_xor(p, 32, 64);
        if (kq == 0) atomicAdd(&ksum[seq * DIM + n00 + j * 16], p);
      }
    }
  }
}

// kvT[seq][e][d] = sum_s VT[seq][e][s] * KT[seq][d][s].
// r13 form: 128x256 tile, BK=64, dbuf/1-barrier, 256 blocks = exactly 1/CU
// (co-residency impossible at this grid, so dbuf is the right choice here).
__global__ __launch_bounds__(512, 1) void kv_kernel(
    const __bf16* __restrict__ VT, const __bf16* __restrict__ KT,
    __bf16* __restrict__ kvT)
{
  __shared__ __align__(16) __bf16 As[2][128 * 64];   // 16KB x2
  __shared__ __align__(16) __bf16 Bs[2][256 * 64];   // 32KB x2
  const int b = blockIdx.x;
  const int xcd = b & 7, loc = b >> 3;
  const int seq = (loc >> 3) * 8 + xcd;          // 32 seqs, pinned per XCD
  const int inner = loc & 7;
  const int mt = inner >> 1, nt = inner & 1;     // 4 M-tiles x 2 N-tiles

  const int tid = threadIdx.x, wave = tid >> 6, lane = tid & 63;
  const int wr = wave >> 2, wn = wave & 3;       // 2M x 4N: 64 rows x 64 cols
  const int lr = lane & 15, kq = lane >> 4;

  const __bf16* Abase = VT + (size_t)seq * DIM * SLEN + (size_t)(mt * 128) * SLEN;
  const __bf16* Bbase = KT + (size_t)seq * DIM * SLEN + (size_t)(nt * 256) * SLEN;

  auto stage = [&](int s, int kt) {
#pragma unroll
    for (int q = 0; q < 2; ++q) {                // A: 16KB
      const int L  = q * 8192 + tid * 16;
      const int r  = L >> 7;
      const int sl = (L >> 4) & 7;
      const int c  = ((sl ^ (r & 7)) << 3);
      load_lds16(Abase + (size_t)r * SLEN + (kt + c),
                 (char*)(&As[s][0]) + q * 8192 + wave * 1024);
    }
#pragma unroll
    for (int q = 0; q < 4; ++q) {                // B: 32KB
      const int L  = q * 8192 + tid * 16;
      const int r  = L >> 7;
      const int sl = (L >> 4) & 7;
      const int c  = ((sl ^ (r & 7)) << 3);
      load_lds16(Bbase + (size_t)r * SLEN + (kt + c),
                 (char*)(&Bs[s][0]) + q * 8192 + wave * 1024);
    }
  };

  f32x4 acc[4][4] = {};

  stage(0, 0);
  __syncthreads();
  for (int t = 0; t < 32; ++t) {
    const int cur = t & 1;
    if (t < 31) stage(cur ^ 1, (t + 1) * 64);
#pragma unroll
    for (int kk = 0; kk < 2; ++kk) {
      bf16x8 bfr[4], af[4];
#pragma unroll
      for (int j = 0; j < 4; ++j) {
        const int rB = wn * 64 + j * 16 + lr;
        bfr[j] = *reinterpret_cast<const bf16x8*>(
            (const char*)(&Bs[cur][0]) + rB * 128 + (((kk * 4 + kq) ^ (rB & 7)) << 4));
      }
#pragma unroll
      for (int i = 0; i < 4; ++i) {
        const int rA = wr * 64 + i * 16 + lr;
        af[i] = *reinterpret_cast<const bf16x8*>(
            (const char*)(&As[cur][0]) + rA * 128 + (((kk * 4 + kq) ^ (rA & 7)) << 4));
      }
#pragma unroll
      for (int i = 0; i < 4; ++i)
#pragma unroll
        for (int j = 0; j < 4; ++j)
          acc[i][j] = __builtin_amdgcn_mfma_f32_16x16x32_bf16(af[i], bfr[j], acc[i][j], 0, 0, 0);
    }
    __syncthreads();
  }

  const int m0 = mt * 128 + wr * 64 + kq * 4;
  const int n0 = nt * 256 + wn * 64 + lr;
  __bf16* C = kvT + (size_t)seq * DIM * DIM;
#pragma unroll
  for (int i = 0; i < 4; ++i)
#pragma unroll
    for (int j = 0; j < 4; ++j)
#pragma unroll
      for (int r = 0; r < 4; ++r)
        C[(size_t)(m0 + i * 16 + r) * DIM + (n0 + j * 16)] = (__bf16)acc[i][j][r];
}

// out[m,e] = (sum_d Q[m,d]*kvT[seq][e][d]) / den[m], den fused as extra MFMA
// column (verified r11). Single-buffer 64KB + 2-barrier (same conversion as
// qkv): 512 blocks -> 2 blocks/CU co-resident.
__global__ __launch_bounds__(512, 4) void num_kernel(
    const __bf16* __restrict__ Q, const __bf16* __restrict__ kvT,
    const float* __restrict__ ksum, __bf16* __restrict__ out)
{
  __shared__ __align__(16) __bf16 As[256 * 64];   // 32KB
  __shared__ __align__(16) __bf16 Bs[256 * 64];   // 32KB
  __shared__ __align__(16) __bf16 ks_lds[512];    // 1KB
  const int b = blockIdx.x;
  const int xcd = b & 7, loc = b >> 3;
  const int seq = (loc >> 4) * 8 + xcd;          // 4 seqs per XCD pass
  const int inner = loc & 15;
  const int brow = inner >> 1, bcol = inner & 1; // 8 x 2 tiles per seq
  const size_t grow0 = (size_t)seq * SLEN + brow * 256;

  const int tid = threadIdx.x, wave = tid >> 6, lane = tid & 63;
  const int wr = wave >> 2, wn = wave & 3;
  const int lr = lane & 15, kq = lane >> 4;

  const __bf16* Abase = Q + grow0 * DIM;
  const __bf16* Bbase = kvT + (size_t)seq * DIM * DIM + (size_t)(bcol * 256) * DIM;

  auto stage = [&](int kt) {
#pragma unroll
    for (int q = 0; q < 4; ++q) {
      const int L  = q * 8192 + tid * 16;
      const int r  = L >> 7;
      const int sl = (L >> 4) & 7;
      const int c  = ((sl ^ (r & 7)) << 3);
      load_lds16(Abase + (size_t)r * DIM + (kt + c),
                 (char*)As + q * 8192 + wave * 1024);
      load_lds16(Bbase + (size_t)r * DIM + (kt + c),
                 (char*)Bs + q * 8192 + wave * 1024);
    }
  };

  f32x4 acc[8][4] = {};
  f32x4 accd[8] = {};

  ks_lds[tid] = (__bf16)ksum[seq * DIM + tid];   // covered by first barrier
  for (int t = 0; t < 8; ++t) {
    stage(t * 64);
    __syncthreads();
#pragma unroll
    for (int kk = 0; kk < 2; ++kk) {
      bf16x8 bfr[4], af[8];
      const bf16x8 ksf = *reinterpret_cast<const bf16x8*>(
          &ks_lds[t * 64 + kk * 32 + kq * 8]);   // same addr across lr: broadcast
#pragma unroll
      for (int j = 0; j < 4; ++j) {
        const int rB = wn * 64 + j * 16 + lr;
        bfr[j] = *reinterpret_cast<const bf16x8*>(
            (const char*)Bs + rB * 128 + (((kk * 4 + kq) ^ (rB & 7)) << 4));
      }
#pragma unroll
      for (int i = 0; i < 8; ++i) {
        const int rA = wr * 128 + i * 16 + lr;
        af[i] = *reinterpret_cast<const bf16x8*>(
            (const char*)As + rA * 128 + (((kk * 4 + kq) ^ (rA & 7)) << 4));
      }
#pragma unroll
      for (int i = 0; i < 8; ++i) {
#pragma unroll
        for (int j = 0; j < 4; ++j)
          acc[i][j] = __builtin_amdgcn_mfma_f32_16x16x32_bf16(af[i], bfr[j], acc[i][j], 0, 0, 0);
        accd[i] = __builtin_amdgcn_mfma_f32_16x16x32_bf16(af[i], ksf, accd[i], 0, 0, 0);
      }
    }
    __syncthreads();
  }

  // epilogue: rden from fused den (already in epilogue row layout), write bf16
  const size_t g0 = grow0 + wr * 128 + kq * 4;
  const int n00 = bcol * 256 + wn * 64 + lr;
#pragma unroll
  for (int i = 0; i < 8; ++i) {
    float rd[4];
#pragma unroll
    for (int r = 0; r < 4; ++r)
      rd[r] = 1.f / fmaxf(accd[i][r], 1e-6f);
#pragma unroll
    for (int j = 0; j < 4; ++j)
#pragma unroll
      for (int r = 0; r < 4; ++r)
        out[(g0 + i * 16 + r) * DIM + (n00 + j * 16)] =
            (__bf16)(acc[i][j][r] * rd[r]);
  }
}

// Fused out-proj + bias + residual + LayerNorm. 128 rows x 512 cols/block,
// 512 threads, wave layout 2Mx4N, double-buffered, one __syncthreads/K-step.
// At its HBM-write floor (~52us) — unchanged.
__global__ __launch_bounds__(512, 1) void final_kernel(
    const __bf16* __restrict__ outb, const __bf16* __restrict__ Wob,
    const float* __restrict__ bo, const float* __restrict__ gamma,
    const float* __restrict__ beta, float* __restrict__ y)
{
  __shared__ __align__(16) __bf16 Asm[2][128 * 32];   // 8KB x2
  __shared__ __align__(16) __bf16 Bsm[2][512 * 32];   // 32KB x2
  __shared__ float redS[4][128], redSS[4][128];
  const int tid = threadIdx.x, wave = tid >> 6, lane = tid & 63;
  const int Wr = wave >> 2, Wc = wave & 3;            // 2M x 4N: 64 rows x 128 cols
  const int lr = lane & 15, kq = lane >> 4;
  const int brow = blockIdx.x;
  f32x4 acc[4][8] = {};

  auto stage = [&](int s, int kt) {
    {
      const int L = tid * 16;
      const int r = L >> 6, sl = (L >> 4) & 3;
      const int c = ((sl ^ ((r >> 1) & 3)) << 3);
      load_lds16(outb + (size_t)(brow * 128 + r) * DIM + (kt + c),
                 (char*)(&Asm[s][0]) + wave * 1024);
    }
#pragma unroll
    for (int q = 0; q < 4; ++q) {
      const int L = q * 8192 + tid * 16;
      const int r = L >> 6, sl = (L >> 4) & 3;
      const int c = ((sl ^ ((r >> 1) & 3)) << 3);
      load_lds16(Wob + (size_t)r * DIM + (kt + c),
                 (char*)(&Bsm[s][0]) + q * 8192 + wave * 1024);
    }
  };

  stage(0, 0);
  __syncthreads();
  for (int t = 0; t < 16; ++t) {
    const int cur = t & 1;
    if (t < 15) stage(cur ^ 1, (t + 1) * 32);
    bf16x8 af[4];
#pragma unroll
    for (int i = 0; i < 4; ++i) {
      const int rA = Wr * 64 + i * 16 + lr;
      af[i] = *reinterpret_cast<const bf16x8*>(
          (char*)(&Asm[cur][0]) + rA * 64 + ((kq ^ ((rA >> 1) & 3)) << 4));
    }
#pragma unroll
    for (int j = 0; j < 8; ++j) {
      const int rB = Wc * 128 + j * 16 + lr;
      bf16x8 bf = *reinterpret_cast<const bf16x8*>(
          (char*)(&Bsm[cur][0]) + rB * 64 + ((kq ^ ((rB >> 1) & 3)) << 4));
#pragma unroll
      for (int i = 0; i < 4; ++i)
        acc[i][j] = __builtin_amdgcn_mfma_f32_16x16x32_bf16(af[i], bf, acc[i][j], 0, 0, 0);
    }
    __syncthreads();
  }

  const int m0g = brow * 128;
  float sA[4][4] = {{0.f}}, ssA[4][4] = {{0.f}};
#pragma unroll
  for (int j = 0; j < 8; ++j) {
    const int n = Wc * 128 + j * 16 + lr;
    const float bon = bo[n];
#pragma unroll
    for (int i = 0; i < 4; ++i) {
      const int mb = m0g + Wr * 64 + i * 16 + kq * 4;
#pragma unroll
      for (int r = 0; r < 4; ++r) {
        float v = acc[i][j][r] + bon + (float)outb[(size_t)(mb + r) * DIM + n];
        acc[i][j][r] = v;
        sA[i][r] += v; ssA[i][r] += v * v;
      }
    }
  }
#pragma unroll
  for (int i = 0; i < 4; ++i)
#pragma unroll
    for (int r = 0; r < 4; ++r) {
      float s = sA[i][r], ss = ssA[i][r];
#pragma unroll
      for (int off = 1; off <= 8; off <<= 1) {
        s  += __shfl_xor(s,  off, 64);
        ss += __shfl_xor(ss, off, 64);
      }
      if (lr == 0) {
        const int ml = Wr * 64 + i * 16 + kq * 4 + r;
        redS[Wc][ml] = s; redSS[Wc][ml] = ss;
      }
    }
  __syncthreads();
  float mu_[4][4], rs_[4][4];
#pragma unroll
  for (int i = 0; i < 4; ++i)
#pragma unroll
    for (int r = 0; r < 4; ++r) {
      const int ml = Wr * 64 + i * 16 + kq * 4 + r;
      const float S  = redS[0][ml] + redS[1][ml] + redS[2][ml] + redS[3][ml];
      const float SS = redSS[0][ml] + redSS[1][ml] + redSS[2][ml] + redSS[3][ml];
      const float mu = S * (1.f / 512.f);
      const float var = SS * (1.f / 512.f) - mu * mu;
      mu_[i][r] = mu;
      rs_[i][r] = rsqrtf(var + 1e-5f);
    }
#pragma unroll
  for (int j = 0; j < 8; ++j) {
    const int n = Wc * 128 + j * 16 + lr;
    const float g = gamma[n], bb = beta[n];
#pragma unroll
    for (int i = 0; i < 4; ++i) {
      const int mb = m0g + Wr * 64 + i * 16 + kq * 4;
#pragma unroll
      for (int r = 0; r < 4; ++r)
        y[(size_t)(mb + r) * DIM + n] = (acc[i][j][r] - mu_[i][r]) * rs_[i][r] * g + bb;
    }
  }
}

// ---------- launch ----------
extern "C" void kernel_launch(void* const* d_in, const int* in_sizes, int n_in,
                              void* d_out, int out_size, void* d_ws, size_t ws_size,
                              hipStream_t stream)
{
  const float* x     = (const float*)d_in[0];
  const float* Wq    = (const float*)d_in[1];
  const float* Wk    = (const float*)d_in[2];
  const float* Wv    = (const float*)d_in[3];
  const float* Wo    = (const float*)d_in[4];
  const float* bo    = (const float*)d_in[5];
  const float* gamma = (const float*)d_in[6];
  const float* beta  = (const float*)d_in[7];
  float* outp = (float*)d_out;

  char* ws = (char*)d_ws;
  const size_t SZ = 67108864;                      // 64 MiB (bf16 [65536][512])
  __bf16* xb   = (__bf16*)(ws + 0);                // reused as `out` after qkv
  __bf16* Q    = (__bf16*)(ws + SZ);
  __bf16* KT   = (__bf16*)(ws + 2 * SZ);
  __bf16* VT   = (__bf16*)(ws + 3 * SZ);
  __bf16* kvT  = (__bf16*)(ws + 4 * SZ);           // 16 MiB
  __bf16* Wqb  = (__bf16*)(ws + 4 * SZ + 16777216);
  __bf16* Wkb  = Wqb + 262144;
  __bf16* Wvb  = Wkb + 262144;
  __bf16* Wob  = Wvb + 262144;
  float*  ksum = (float*)(Wob + 262144);           // 64 KiB

  hipMemsetAsync(ksum, 0, SEQS * DIM * sizeof(float), stream);
  castall_kernel<<<4224, 256, 0, stream>>>(x, xb, Wq, Wk, Wv, Wo,
                                           Wqb, Wkb, Wvb, Wob);

  qkv_kernel<<<1536, 512, 0, stream>>>(xb, Wqb, Wkb, Wvb, Q, KT, VT, ksum);
  kv_kernel<<<256, 512, 0, stream>>>(VT, KT, kvT);
  num_kernel<<<512, 512, 0, stream>>>(Q, kvT, ksum, xb /*out*/);
  final_kernel<<<512, 512, 0, stream>>>(xb, Wob, bo, gamma, beta, outp);
}

// Round 15
// 372.896 us; speedup vs baseline: 4.2674x; 4.2674x over previous
//
#include <hip/hip_runtime.h>
#include <cstdint>

// ---------- types ----------
typedef __bf16 bf16x8 __attribute__((ext_vector_type(8)));
typedef float  f32x4  __attribute__((ext_vector_type(4)));

// Problem constants: BATCH=8, N_SEQS=4, SEQ_LEN=2048, D=512 -> 32 seqs, 65536 rows
#define SEQS   32
#define SLEN   2048
#define DIM    512
#define MROWS  65536

static __device__ __forceinline__ void load_lds16(const void* g, void* l) {
  __builtin_amdgcn_global_load_lds(
      (const __attribute__((address_space(1))) void*)(uintptr_t)g,
      (__attribute__((address_space(3))) void*)(uintptr_t)l,
      16, 0, 0);
}

static __device__ __forceinline__ unsigned short bfbits(float f) {
  __bf16 h = (__bf16)f;
  unsigned short u;
  __builtin_memcpy(&u, &h, 2);
  return u;
}

// ---------- kernels ----------

// One dispatch: cast x (fp32->bf16) plus the 4 weight matrices.
__global__ __launch_bounds__(256) void castall_kernel(
    const float* __restrict__ x, __bf16* __restrict__ xb,
    const float* __restrict__ wq, const float* __restrict__ wk,
    const float* __restrict__ wv, const float* __restrict__ wo,
    __bf16* __restrict__ wqb, __bf16* __restrict__ wkb,
    __bf16* __restrict__ wvb, __bf16* __restrict__ wob)
{
  const int X8 = MROWS * DIM / 8;            // 4,194,304
  const int W8 = DIM * DIM / 8;              // 32,768
  const int total = X8 + 4 * W8;
  int i = blockIdx.x * blockDim.x + threadIdx.x;
  const int stride = gridDim.x * blockDim.x;
  for (; i < total; i += stride) {
    const float* src; __bf16* dst; int off;
    if (i < X8) { src = x; dst = xb; off = i; }
    else {
      const int wsel = (i - X8) / W8;
      off = (i - X8) - wsel * W8;
      src = (wsel == 0) ? wq : (wsel == 1) ? wk : (wsel == 2) ? wv : wo;
      dst = (wsel == 0) ? wqb : (wsel == 1) ? wkb : (wsel == 2) ? wvb : wob;
    }
    const float4* p = reinterpret_cast<const float4*>(src + (size_t)off * 8);
    float4 a = p[0], b2 = p[1];
    float vals[8] = {a.x, a.y, a.z, a.w, b2.x, b2.y, b2.z, b2.w};
    uint32_t w[4];
#pragma unroll
    for (int t = 0; t < 4; ++t)
      w[t] = (uint32_t)bfbits(vals[2 * t]) | ((uint32_t)bfbits(vals[2 * t + 1]) << 16);
    uint4 o; o.x = w[0]; o.y = w[1]; o.z = w[2]; o.w = w[3];
    *reinterpret_cast<uint4*>(dst + (size_t)off * 8) = o;
  }
}

// QKV projection: 256x256 tile, 512 threads (8 waves 2Mx4N), BK=64,
// double-buffered LDS (128KB), ONE __syncthreads per K-step (r9/r11/r13
// verified best: 741 TF, 0 conflicts). r14's (512,4) occupancy squeeze
// spilled (VGPR 64 << need ~150) — never cap below measured need (116).
__global__ __launch_bounds__(512, 1) void qkv_kernel(
    const __bf16* __restrict__ xb,
    const __bf16* __restrict__ Wqb, const __bf16* __restrict__ Wkb,
    const __bf16* __restrict__ Wvb,
    __bf16* __restrict__ Q, __bf16* __restrict__ KT, __bf16* __restrict__ VT,
    float* __restrict__ ksum)
{
  __shared__ __align__(16) __bf16 As[2][256 * 64];   // 32KB x2
  __shared__ __align__(16) __bf16 Bs[2][256 * 64];   // 32KB x2
  const int b = blockIdx.x;
  const int xcd = b & 7, loc = b >> 3;
  const int brow = (loc / 6) * 8 + xcd;          // 0..255
  const int inner = loc % 6;
  const int z = inner >> 1, bcol = inner & 1;
  const __bf16* W = (z == 0) ? Wqb : (z == 1) ? Wkb : Wvb;

  const int tid = threadIdx.x, wave = tid >> 6, lane = tid & 63;
  const int wr = wave >> 2, wn = wave & 3;       // 2 M-halves x 4 N-quarters
  const int lr = lane & 15, kq = lane >> 4;

  const __bf16* Abase = xb + (size_t)(brow * 256) * DIM;
  const __bf16* Bbase = W + (size_t)(bcol * 256) * DIM;

  auto stage = [&](int s, int kt) {
#pragma unroll
    for (int q = 0; q < 4; ++q) {
      const int L  = q * 8192 + tid * 16;
      const int r  = L >> 7;
      const int sl = (L >> 4) & 7;
      const int c  = ((sl ^ (r & 7)) << 3);
      load_lds16(Abase + (size_t)r * DIM + (kt + c),
                 (char*)(&As[s][0]) + q * 8192 + wave * 1024);
      load_lds16(Bbase + (size_t)r * DIM + (kt + c),
                 (char*)(&Bs[s][0]) + q * 8192 + wave * 1024);
    }
  };

  f32x4 acc[8][4] = {};

  stage(0, 0);
  __syncthreads();
  for (int t = 0; t < 8; ++t) {
    const int cur = t & 1;
    if (t < 7) stage(cur ^ 1, (t + 1) * 64);
#pragma unroll
    for (int kk = 0; kk < 2; ++kk) {
      bf16x8 bfr[4], af[8];
#pragma unroll
      for (int j = 0; j < 4; ++j) {
        const int rB = wn * 64 + j * 16 + lr;
        bfr[j] = *reinterpret_cast<const bf16x8*>(
            (const char*)(&Bs[cur][0]) + rB * 128 + (((kk * 4 + kq) ^ (rB & 7)) << 4));
      }
#pragma unroll
      for (int i = 0; i < 8; ++i) {
        const int rA = wr * 128 + i * 16 + lr;
        af[i] = *reinterpret_cast<const bf16x8*>(
            (const char*)(&As[cur][0]) + rA * 128 + (((kk * 4 + kq) ^ (rA & 7)) << 4));
      }
#pragma unroll
      for (int i = 0; i < 8; ++i)
#pragma unroll
        for (int j = 0; j < 4; ++j)
          acc[i][j] = __builtin_amdgcn_mfma_f32_16x16x32_bf16(af[i], bfr[j], acc[i][j], 0, 0, 0);
    }
    __syncthreads();
  }

  // epilogue
  const int m00 = brow * 256 + wr * 128 + kq * 4;
  const int n00 = bcol * 256 + wn * 64 + lr;
  if (z == 0) {
#pragma unroll
    for (int i = 0; i < 8; ++i)
#pragma unroll
      for (int j = 0; j < 4; ++j) {
        const int n = n00 + j * 16;
#pragma unroll
        for (int r = 0; r < 4; ++r) {
          const int m = m00 + i * 16 + r;
          float v = acc[i][j][r];
          v = (v > 0.f) ? (v + 1.f) : __expf(v);   // elu(v)+1
          Q[(size_t)m * DIM + n] = (__bf16)v;
        }
      }
  } else {
    __bf16* T = (z == 1) ? KT : VT;
    const int seq = (brow * 256) >> 11;
    float ks[4] = {0.f, 0.f, 0.f, 0.f};
#pragma unroll
    for (int i = 0; i < 8; ++i) {
      const int mb = m00 + i * 16;
      const int s0 = mb & 2047;
#pragma unroll
      for (int j = 0; j < 4; ++j) {
        const int d = n00 + j * 16;
        unsigned short h[4];
#pragma unroll
        for (int r = 0; r < 4; ++r) {
          float v = acc[i][j][r];
          if (z == 1) { v = (v > 0.f) ? (v + 1.f) : __expf(v); ks[j] += v; }
          h[r] = bfbits(v);
        }
        uint2 u;
        u.x = (uint32_t)h[0] | ((uint32_t)h[1] << 16);
        u.y = (uint32_t)h[2] | ((uint32_t)h[3] << 16);
        *reinterpret_cast<uint2*>(T + ((size_t)(seq * DIM + d) << 11) + s0) = u;
      }
    }
    if (z == 1) {
#pragma unroll
      for (int j = 0; j < 4; ++j) {
        float p = ks[j];
        p += __shfl_xor(p, 16, 64);
        p += __shfl_xor(p, 32, 64);
        if (kq == 0) atomicAdd(&ksum[seq * DIM + n00 + j * 16], p);
      }
    }
  }
}

// kvT[seq][e][d] = sum_s VT[seq][e][s] * KT[seq][d][s].
// r13 form: 128x256 tile, BK=64, dbuf/1-barrier, 256 blocks = exactly 1/CU.
__global__ __launch_bounds__(512, 1) void kv_kernel(
    const __bf16* __restrict__ VT, const __bf16* __restrict__ KT,
    __bf16* __restrict__ kvT)
{
  __shared__ __align__(16) __bf16 As[2][128 * 64];   // 16KB x2
  __shared__ __align__(16) __bf16 Bs[2][256 * 64];   // 32KB x2
  const int b = blockIdx.x;
  const int xcd = b & 7, loc = b >> 3;
  const int seq = (loc >> 3) * 8 + xcd;          // 32 seqs, pinned per XCD
  const int inner = loc & 7;
  const int mt = inner >> 1, nt = inner & 1;     // 4 M-tiles x 2 N-tiles

  const int tid = threadIdx.x, wave = tid >> 6, lane = tid & 63;
  const int wr = wave >> 2, wn = wave & 3;       // 2M x 4N: 64 rows x 64 cols
  const int lr = lane & 15, kq = lane >> 4;

  const __bf16* Abase = VT + (size_t)seq * DIM * SLEN + (size_t)(mt * 128) * SLEN;
  const __bf16* Bbase = KT + (size_t)seq * DIM * SLEN + (size_t)(nt * 256) * SLEN;

  auto stage = [&](int s, int kt) {
#pragma unroll
    for (int q = 0; q < 2; ++q) {                // A: 16KB
      const int L  = q * 8192 + tid * 16;
      const int r  = L >> 7;
      const int sl = (L >> 4) & 7;
      const int c  = ((sl ^ (r & 7)) << 3);
      load_lds16(Abase + (size_t)r * SLEN + (kt + c),
                 (char*)(&As[s][0]) + q * 8192 + wave * 1024);
    }
#pragma unroll
    for (int q = 0; q < 4; ++q) {                // B: 32KB
      const int L  = q * 8192 + tid * 16;
      const int r  = L >> 7;
      const int sl = (L >> 4) & 7;
      const int c  = ((sl ^ (r & 7)) << 3);
      load_lds16(Bbase + (size_t)r * SLEN + (kt + c),
                 (char*)(&Bs[s][0]) + q * 8192 + wave * 1024);
    }
  };

  f32x4 acc[4][4] = {};

  stage(0, 0);
  __syncthreads();
  for (int t = 0; t < 32; ++t) {
    const int cur = t & 1;
    if (t < 31) stage(cur ^ 1, (t + 1) * 64);
#pragma unroll
    for (int kk = 0; kk < 2; ++kk) {
      bf16x8 bfr[4], af[4];
#pragma unroll
      for (int j = 0; j < 4; ++j) {
        const int rB = wn * 64 + j * 16 + lr;
        bfr[j] = *reinterpret_cast<const bf16x8*>(
            (const char*)(&Bs[cur][0]) + rB * 128 + (((kk * 4 + kq) ^ (rB & 7)) << 4));
      }
#pragma unroll
      for (int i = 0; i < 4; ++i) {
        const int rA = wr * 64 + i * 16 + lr;
        af[i] = *reinterpret_cast<const bf16x8*>(
            (const char*)(&As[cur][0]) + rA * 128 + (((kk * 4 + kq) ^ (rA & 7)) << 4));
      }
#pragma unroll
      for (int i = 0; i < 4; ++i)
#pragma unroll
        for (int j = 0; j < 4; ++j)
          acc[i][j] = __builtin_amdgcn_mfma_f32_16x16x32_bf16(af[i], bfr[j], acc[i][j], 0, 0, 0);
    }
    __syncthreads();
  }

  const int m0 = mt * 128 + wr * 64 + kq * 4;
  const int n0 = nt * 256 + wn * 64 + lr;
  __bf16* C = kvT + (size_t)seq * DIM * DIM;
#pragma unroll
  for (int i = 0; i < 4; ++i)
#pragma unroll
    for (int j = 0; j < 4; ++j)
#pragma unroll
      for (int r = 0; r < 4; ++r)
        C[(size_t)(m0 + i * 16 + r) * DIM + (n0 + j * 16)] = (__bf16)acc[i][j][r];
}

// out[m,e] = (sum_d Q[m,d]*kvT[seq][e][d]) / den[m], den fused as extra MFMA
// column (verified r11). One __syncthreads per K-step (r11/r13 form).
__global__ __launch_bounds__(512, 1) void num_kernel(
    const __bf16* __restrict__ Q, const __bf16* __restrict__ kvT,
    const float* __restrict__ ksum, __bf16* __restrict__ out)
{
  __shared__ __align__(16) __bf16 As[2][256 * 64];   // 32KB x2
  __shared__ __align__(16) __bf16 Bs[2][256 * 64];   // 32KB x2
  __shared__ __align__(16) __bf16 ks_lds[512];       // 1KB
  const int b = blockIdx.x;
  const int xcd = b & 7, loc = b >> 3;
  const int seq = (loc >> 4) * 8 + xcd;          // 4 seqs per XCD pass
  const int inner = loc & 15;
  const int brow = inner >> 1, bcol = inner & 1; // 8 x 2 tiles per seq
  const size_t grow0 = (size_t)seq * SLEN + brow * 256;

  const int tid = threadIdx.x, wave = tid >> 6, lane = tid & 63;
  const int wr = wave >> 2, wn = wave & 3;
  const int lr = lane & 15, kq = lane >> 4;

  const __bf16* Abase = Q + grow0 * DIM;
  const __bf16* Bbase = kvT + (size_t)seq * DIM * DIM + (size_t)(bcol * 256) * DIM;

  auto stage = [&](int s, int kt) {
#pragma unroll
    for (int q = 0; q < 4; ++q) {
      const int L  = q * 8192 + tid * 16;
      const int r  = L >> 7;
      const int sl = (L >> 4) & 7;
      const int c  = ((sl ^ (r & 7)) << 3);
      load_lds16(Abase + (size_t)r * DIM + (kt + c),
                 (char*)(&As[s][0]) + q * 8192 + wave * 1024);
      load_lds16(Bbase + (size_t)r * DIM + (kt + c),
                 (char*)(&Bs[s][0]) + q * 8192 + wave * 1024);
    }
  };

  f32x4 acc[8][4] = {};
  f32x4 accd[8] = {};

  ks_lds[tid] = (__bf16)ksum[seq * DIM + tid];   // 512 threads, one each
  stage(0, 0);
  __syncthreads();
  for (int t = 0; t < 8; ++t) {
    const int cur = t & 1;
    if (t < 7) stage(cur ^ 1, (t + 1) * 64);
#pragma unroll
    for (int kk = 0; kk < 2; ++kk) {
      bf16x8 bfr[4], af[8];
      const bf16x8 ksf = *reinterpret_cast<const bf16x8*>(
          &ks_lds[t * 64 + kk * 32 + kq * 8]);   // same addr across lr: broadcast
#pragma unroll
      for (int j = 0; j < 4; ++j) {
        const int rB = wn * 64 + j * 16 + lr;
        bfr[j] = *reinterpret_cast<const bf16x8*>(
            (const char*)(&Bs[cur][0]) + rB * 128 + (((kk * 4 + kq) ^ (rB & 7)) << 4));
      }
#pragma unroll
      for (int i = 0; i < 8; ++i) {
        const int rA = wr * 128 + i * 16 + lr;
        af[i] = *reinterpret_cast<const bf16x8*>(
            (const char*)(&As[cur][0]) + rA * 128 + (((kk * 4 + kq) ^ (rA & 7)) << 4));
      }
#pragma unroll
      for (int i = 0; i < 8; ++i) {
#pragma unroll
        for (int j = 0; j < 4; ++j)
          acc[i][j] = __builtin_amdgcn_mfma_f32_16x16x32_bf16(af[i], bfr[j], acc[i][j], 0, 0, 0);
        accd[i] = __builtin_amdgcn_mfma_f32_16x16x32_bf16(af[i], ksf, accd[i], 0, 0, 0);
      }
    }
    __syncthreads();
  }

  // epilogue: rden from fused den (already in epilogue row layout), write bf16
  const size_t g0 = grow0 + wr * 128 + kq * 4;
  const int n00 = bcol * 256 + wn * 64 + lr;
#pragma unroll
  for (int i = 0; i < 8; ++i) {
    float rd[4];
#pragma unroll
    for (int r = 0; r < 4; ++r)
      rd[r] = 1.f / fmaxf(accd[i][r], 1e-6f);
#pragma unroll
    for (int j = 0; j < 4; ++j)
#pragma unroll
      for (int r = 0; r < 4; ++r)
        out[(g0 + i * 16 + r) * DIM + (n00 + j * 16)] =
            (__bf16)(acc[i][j][r] * rd[r]);
  }
}

// Fused out-proj + bias + residual + LayerNorm. 128 rows x 512 cols/block,
// 512 threads, wave layout 2Mx4N, double-buffered, one __syncthreads/K-step.
__global__ __launch_bounds__(512, 1) void final_kernel(
    const __bf16* __restrict__ outb, const __bf16* __restrict__ Wob,
    const float* __restrict__ bo, const float* __restrict__ gamma,
    const float* __restrict__ beta, float* __restrict__ y)
{
  __shared__ __align__(16) __bf16 Asm[2][128 * 32];   // 8KB x2
  __shared__ __align__(16) __bf16 Bsm[2][512 * 32];   // 32KB x2
  __shared__ float redS[4][128], redSS[4][128];
  const int tid = threadIdx.x, wave = tid >> 6, lane = tid & 63;
  const int Wr = wave >> 2, Wc = wave & 3;            // 2M x 4N: 64 rows x 128 cols
  const int lr = lane & 15, kq = lane >> 4;
  const int brow = blockIdx.x;
  f32x4 acc[4][8] = {};

  auto stage = [&](int s, int kt) {
    {
      const int L = tid * 16;
      const int r = L >> 6, sl = (L >> 4) & 3;
      const int c = ((sl ^ ((r >> 1) & 3)) << 3);
      load_lds16(outb + (size_t)(brow * 128 + r) * DIM + (kt + c),
                 (char*)(&Asm[s][0]) + wave * 1024);
    }
#pragma unroll
    for (int q = 0; q < 4; ++q) {
      const int L = q * 8192 + tid * 16;
      const int r = L >> 6, sl = (L >> 4) & 3;
      const int c = ((sl ^ ((r >> 1) & 3)) << 3);
      load_lds16(Wob + (size_t)r * DIM + (kt + c),
                 (char*)(&Bsm[s][0]) + q * 8192 + wave * 1024);
    }
  };

  stage(0, 0);
  __syncthreads();
  for (int t = 0; t < 16; ++t) {
    const int cur = t & 1;
    if (t < 15) stage(cur ^ 1, (t + 1) * 32);
    bf16x8 af[4];
#pragma unroll
    for (int i = 0; i < 4; ++i) {
      const int rA = Wr * 64 + i * 16 + lr;
      af[i] = *reinterpret_cast<const bf16x8*>(
          (char*)(&Asm[cur][0]) + rA * 64 + ((kq ^ ((rA >> 1) & 3)) << 4));
    }
#pragma unroll
    for (int j = 0; j < 8; ++j) {
      const int rB = Wc * 128 + j * 16 + lr;
      bf16x8 bf = *reinterpret_cast<const bf16x8*>(
          (char*)(&Bsm[cur][0]) + rB * 64 + ((kq ^ ((rB >> 1) & 3)) << 4));
#pragma unroll
      for (int i = 0; i < 4; ++i)
        acc[i][j] = __builtin_amdgcn_mfma_f32_16x16x32_bf16(af[i], bf, acc[i][j], 0, 0, 0);
    }
    __syncthreads();
  }

  const int m0g = brow * 128;
  float sA[4][4] = {{0.f}}, ssA[4][4] = {{0.f}};
#pragma unroll
  for (int j = 0; j < 8; ++j) {
    const int n = Wc * 128 + j * 16 + lr;
    const float bon = bo[n];
#pragma unroll
    for (int i = 0; i < 4; ++i) {
      const int mb = m0g + Wr * 64 + i * 16 + kq * 4;
#pragma unroll
      for (int r = 0; r < 4; ++r) {
        float v = acc[i][j][r] + bon + (float)outb[(size_t)(mb + r) * DIM + n];
        acc[i][j][r] = v;
        sA[i][r] += v; ssA[i][r] += v * v;
      }
    }
  }
#pragma unroll
  for (int i = 0; i < 4; ++i)
#pragma unroll
    for (int r = 0; r < 4; ++r) {
      float s = sA[i][r], ss = ssA[i][r];
#pragma unroll
      for (int off = 1; off <= 8; off <<= 1) {
        s  += __shfl_xor(s,  off, 64);
        ss += __shfl_xor(ss, off, 64);
      }
      if (lr == 0) {
        const int ml = Wr * 64 + i * 16 + kq * 4 + r;
        redS[Wc][ml] = s; redSS[Wc][ml] = ss;
      }
    }
  __syncthreads();
  float mu_[4][4], rs_[4][4];
#pragma unroll
  for (int i = 0; i < 4; ++i)
#pragma unroll
    for (int r = 0; r < 4; ++r) {
      const int ml = Wr * 64 + i * 16 + kq * 4 + r;
      const float S  = redS[0][ml] + redS[1][ml] + redS[2][ml] + redS[3][ml];
      const float SS = redSS[0][ml] + redSS[1][ml] + redSS[2][ml] + redSS[3][ml];
      const float mu = S * (1.f / 512.f);
      const float var = SS * (1.f / 512.f) - mu * mu;
      mu_[i][r] = mu;
      rs_[i][r] = rsqrtf(var + 1e-5f);
    }
#pragma unroll
  for (int j = 0; j < 8; ++j) {
    const int n = Wc * 128 + j * 16 + lr;
    const float g = gamma[n], bb = beta[n];
#pragma unroll
    for (int i = 0; i < 4; ++i) {
      const int mb = m0g + Wr * 64 + i * 16 + kq * 4;
#pragma unroll
      for (int r = 0; r < 4; ++r)
        y[(size_t)(mb + r) * DIM + n] = (acc[i][j][r] - mu_[i][r]) * rs_[i][r] * g + bb;
    }
  }
}

// ---------- launch ----------
extern "C" void kernel_launch(void* const* d_in, const int* in_sizes, int n_in,
                              void* d_out, int out_size, void* d_ws, size_t ws_size,
                              hipStream_t stream)
{
  const float* x     = (const float*)d_in[0];
  const float* Wq    = (const float*)d_in[1];
  const float* Wk    = (const float*)d_in[2];
  const float* Wv    = (const float*)d_in[3];
  const float* Wo    = (const float*)d_in[4];
  const float* bo    = (const float*)d_in[5];
  const float* gamma = (const float*)d_in[6];
  const float* beta  = (const float*)d_in[7];
  float* outp = (float*)d_out;

  char* ws = (char*)d_ws;
  const size_t SZ = 67108864;                      // 64 MiB (bf16 [65536][512])
  __bf16* xb   = (__bf16*)(ws + 0);                // reused as `out` after qkv
  __bf16* Q    = (__bf16*)(ws + SZ);
  __bf16* KT   = (__bf16*)(ws + 2 * SZ);
  __bf16* VT   = (__bf16*)(ws + 3 * SZ);
  __bf16* kvT  = (__bf16*)(ws + 4 * SZ);           // 16 MiB
  __bf16* Wqb  = (__bf16*)(ws + 4 * SZ + 16777216);
  __bf16* Wkb  = Wqb + 262144;
  __bf16* Wvb  = Wkb + 262144;
  __bf16* Wob  = Wvb + 262144;
  float*  ksum = (float*)(Wob + 262144);           // 64 KiB

  hipMemsetAsync(ksum, 0, SEQS * DIM * sizeof(float), stream);
  castall_kernel<<<4224, 256, 0, stream>>>(x, xb, Wq, Wk, Wv, Wo,
                                           Wqb, Wkb, Wvb, Wob);

  qkv_kernel<<<1536, 512, 0, stream>>>(xb, Wqb, Wkb, Wvb, Q, KT, VT, ksum);
  kv_kernel<<<256, 512, 0, stream>>>(VT, KT, kvT);
  num_kernel<<<512, 512, 0, stream>>>(Q, kvT, ksum, xb /*out*/);
  final_kernel<<<512, 512, 0, stream>>>(xb, Wob, bo, gamma, beta, outp);
}